// Round 5
// baseline (742.799 us; speedup 1.0000x reference)
//
#include <hip/hip_runtime.h>
#include <hip/hip_bf16.h>

#define N_NODES 50000
#define N_EDGES 250000
#define DIN_ 256
#define DOUT_ 256
#define OH_ 16
#define KF_ 288   // 256 (h) + 16 (degrees) + 16 zero-pad -> 9 K-steps of 32
#define NBLK_EDGE ((N_EDGES + 63) / 64)     // 3907
#define SCAN_TOT (2 * N_NODES)              // 100000
#define SCAN_NB ((SCAN_TOT + 255) / 256)    // 391

typedef short short8 __attribute__((ext_vector_type(8)));
typedef float f32x4 __attribute__((ext_vector_type(4)));

__device__ __forceinline__ unsigned short f2bf(float f) {
    unsigned u = __builtin_bit_cast(unsigned, f);
    return (unsigned short)((u + 0x7fffu + ((u >> 16) & 1u)) >> 16);
}

__device__ __forceinline__ uint4 pack8(float f0, float f1, float f2, float f3,
                                       float f4, float f5, float f6, float f7) {
    uint4 u;
    u.x = (unsigned)f2bf(f0) | ((unsigned)f2bf(f1) << 16);
    u.y = (unsigned)f2bf(f2) | ((unsigned)f2bf(f3) << 16);
    u.z = (unsigned)f2bf(f4) | ((unsigned)f2bf(f5) << 16);
    u.w = (unsigned)f2bf(f6) | ((unsigned)f2bf(f7) << 16);
    return u;
}

__device__ __forceinline__ float fast_rcp(float x) {
#if __has_builtin(__builtin_amdgcn_rcpf)
    return __builtin_amdgcn_rcpf(x);
#else
    return 1.0f / x;
#endif
}

// async global -> LDS, 16 bytes per lane (dest = wave-uniform base + lane*16)
__device__ __forceinline__ void gl_lds16(const void* g, void* l) {
    __builtin_amdgcn_global_load_lds(
        (const __attribute__((address_space(1))) unsigned int*)g,
        (__attribute__((address_space(3))) unsigned int*)l, 16, 0, 0);
}

// counted-vmcnt barriers (T4): keep next-step prefetch in flight across barrier
__device__ __forceinline__ void wait_vm6_barrier() {
    asm volatile("s_waitcnt vmcnt(6)" ::: "memory");
    __builtin_amdgcn_sched_barrier(0);
    __builtin_amdgcn_s_barrier();
    __builtin_amdgcn_sched_barrier(0);
}
__device__ __forceinline__ void wait_vm0_barrier() {
    asm volatile("s_waitcnt vmcnt(0)" ::: "memory");
    __builtin_amdgcn_sched_barrier(0);
    __builtin_amdgcn_s_barrier();
    __builtin_amdgcn_sched_barrier(0);
}
__device__ __forceinline__ void wait_lgkm_barrier() {
    asm volatile("s_waitcnt lgkmcnt(0)" ::: "memory");
    __builtin_amdgcn_sched_barrier(0);
    __builtin_amdgcn_s_barrier();
    __builtin_amdgcn_sched_barrier(0);
}

// ---------- sort pipeline: counting sort of edges by scatter target ----------
__global__ void hist_kernel(const int* __restrict__ sc0, const int* __restrict__ sc1,
                            int* __restrict__ hist) {
    int e = blockIdx.x * 256 + threadIdx.x;
    if (e < N_EDGES) {
        atomicAdd(&hist[sc0[e]], 1);
        atomicAdd(&hist[N_NODES + sc1[e]], 1);
    }
}

__global__ void scan_pass1(const int* __restrict__ hist, int* __restrict__ partials) {
    __shared__ int sdata[256];
    int gid = blockIdx.x * 256 + threadIdx.x;
    sdata[threadIdx.x] = (gid < SCAN_TOT) ? hist[gid] : 0;
    __syncthreads();
    for (int d = 128; d > 0; d >>= 1) {
        if (threadIdx.x < d) sdata[threadIdx.x] += sdata[threadIdx.x + d];
        __syncthreads();
    }
    if (threadIdx.x == 0) partials[blockIdx.x] = sdata[0];
}

__global__ __launch_bounds__(512) void scan_pass2(int* __restrict__ partials) {
    __shared__ int s[512];
    int t = threadIdx.x;
    s[t] = (t < SCAN_NB) ? partials[t] : 0;
    __syncthreads();
    for (int d = 1; d < 512; d <<= 1) {
        int add = (t >= d) ? s[t - d] : 0;
        __syncthreads();
        s[t] += add;
        __syncthreads();
    }
    if (t < SCAN_NB) partials[t] = (t == 0) ? 0 : s[t - 1];   // exclusive
}

__global__ void scan_pass3(const int* __restrict__ hist, const int* __restrict__ partials,
                           int* __restrict__ offs) {
    __shared__ int s[256];
    int gid = blockIdx.x * 256 + threadIdx.x;
    int t = threadIdx.x;
    int v = (gid < SCAN_TOT) ? hist[gid] : 0;
    s[t] = v;
    __syncthreads();
    for (int d = 1; d < 256; d <<= 1) {
        int add = (t >= d) ? s[t - d] : 0;
        __syncthreads();
        s[t] += add;
        __syncthreads();
    }
    if (gid < SCAN_TOT) offs[gid] = partials[blockIdx.x] + s[t] - v;  // exclusive
}

__global__ void rank_kernel(const int* __restrict__ sc0, const int* __restrict__ sc1,
                            int* __restrict__ offs, int* __restrict__ order,
                            int* __restrict__ keys) {
    int e = blockIdx.x * 256 + threadIdx.x;
    if (e < N_EDGES) {
        int k0 = sc0[e];
        int p = atomicAdd(&offs[k0], 1);
        order[p] = e; keys[p] = k0;
        int k1 = sc1[e];
        int q = atomicAdd(&offs[N_NODES + k1], 1);
        order[q] = e; keys[q] = k1;
    }
}

// ---------- weight / input prep ----------
__global__ void prep_weights(const float* __restrict__ W_lin,
                             const float* __restrict__ W_k0,
                             const float* __restrict__ W_k1,
                             unsigned short* __restrict__ WT_lin,
                             unsigned short* __restrict__ WT_k0,
                             unsigned short* __restrict__ WT_k1) {
    int idx = blockIdx.x * 256 + threadIdx.x;
    if (idx < DOUT_ * DIN_) {
        int n = idx >> 8, k = idx & 255;
        WT_lin[idx] = f2bf(W_lin[k * DOUT_ + n]);
    }
    if (idx < DOUT_ * KF_) {
        int n = idx / KF_, k = idx - n * KF_;
        float v0 = 0.f, v1 = 0.f;
        if (k < DIN_ + OH_) {
            v0 = W_k0[k * DOUT_ + n];
            v1 = W_k1[k * DOUT_ + n];
        }
        WT_k0[idx] = f2bf(v0);
        WT_k1[idx] = f2bf(v1);
    }
}

__global__ void conv_h(const float* __restrict__ h, unsigned short* __restrict__ hbf) {
    int idx = blockIdx.x * 256 + threadIdx.x;
    const float4* s = (const float4*)(h + (size_t)idx * 8);
    float4 a = s[0], b = s[1];
    ((uint4*)hbf)[idx] = pack8(a.x, a.y, a.z, a.w, b.x, b.y, b.z, b.w);
}

// h3 = h @ W_lin + b_lin   (writes all of d_out)
__global__ __launch_bounds__(256) void main_gemm(const unsigned short* __restrict__ hbf,
                                                 const unsigned short* __restrict__ WT,
                                                 const float* __restrict__ bias,
                                                 float* __restrict__ out) {
    __shared__ unsigned short Alds[2][64][32];
    __shared__ unsigned short Blds[2][256][32];
    __shared__ float bias_lds[256];
    int tid = threadIdx.x;
    int w = tid >> 6, ln = tid & 63, l15 = ln & 15;
    int row0 = blockIdx.x * 64;
    bias_lds[tid] = bias[tid];

    int ar = row0 + w * 16 + (ln >> 2);
    if (ar >= N_NODES) ar = N_NODES - 1;
    int qs = (ln & 3) ^ ((ln >> 3) & 3);
    const unsigned short* asrc = hbf + (size_t)ar * DIN_ + qs * 8;
    int brow = w * 64;
    int swz = ((ln >> 4) ^ ((l15 >> 1) & 3)) * 8;

    f32x4 acc[16];
#pragma unroll
    for (int j = 0; j < 16; ++j) acc[j] = (f32x4)(0.f);

    gl_lds16(asrc, &Alds[0][w * 16][0]);
#pragma unroll
    for (int i = 0; i < 4; ++i) {
        int n = brow + i * 16 + (ln >> 2);
        gl_lds16(WT + (size_t)n * DIN_ + qs * 8, &Blds[0][brow + i * 16][0]);
    }
    __syncthreads();

    int buf = 0;
    for (int kk = 0; kk < 8; ++kk) {
        if (kk < 7) {
            gl_lds16(asrc + (kk + 1) * 32, &Alds[buf ^ 1][w * 16][0]);
#pragma unroll
            for (int i = 0; i < 4; ++i) {
                int n = brow + i * 16 + (ln >> 2);
                gl_lds16(WT + (size_t)n * DIN_ + (kk + 1) * 32 + qs * 8,
                         &Blds[buf ^ 1][brow + i * 16][0]);
            }
        }
        short8 af = *(const short8*)&Alds[buf][w * 16 + l15][swz];
#pragma unroll
        for (int j = 0; j < 16; ++j) {
            short8 bf = *(const short8*)&Blds[buf][j * 16 + l15][swz];
            acc[j] = __builtin_amdgcn_mfma_f32_16x16x32_bf16(af, bf, acc[j], 0, 0, 0);
        }
        __syncthreads();
        buf ^= 1;
    }

    int rbase = row0 + w * 16 + ((ln >> 4) << 2);
#pragma unroll
    for (int j = 0; j < 16; ++j) {
        int n = j * 16 + l15;
        float bv = bias_lds[n];
#pragma unroll
        for (int i = 0; i < 4; ++i) {
            int rr = rbase + i;
            if (rr < N_NODES) out[(size_t)rr * DOUT_ + n] = acc[j][i] + bv;
        }
    }
}

// Both key terms in one launch; counted-vmcnt pipelined K-loop.
__global__ __launch_bounds__(256) void edge_gemm(const unsigned short* __restrict__ hbf,
                                                 const int* __restrict__ pairs0,
                                                 const int* __restrict__ pairs1,
                                                 const float* __restrict__ deg0,
                                                 const float* __restrict__ deg1,
                                                 const int* __restrict__ order_all, // [2E]
                                                 const int* __restrict__ keys_all,  // [2E]
                                                 const unsigned short* __restrict__ WT0,
                                                 const unsigned short* __restrict__ WT1,
                                                 const float* __restrict__ bias0,
                                                 const float* __restrict__ bias1,
                                                 const float* __restrict__ eps0,
                                                 const float* __restrict__ eps1,
                                                 float* __restrict__ out) {
    __shared__ unsigned short Alds[2][2][64][32];   // 16 KB
    __shared__ unsigned short Blds[2][256][32];     // 32 KB (reused as reduction buf)
    __shared__ float bias_lds[256];
    __shared__ int tgt[64];
    int kb = (blockIdx.x >= NBLK_EDGE) ? 1 : 0;
    int bx = blockIdx.x - kb * NBLK_EDGE;
    const int* pairs = kb ? pairs1 : pairs0;
    const float* degrees = kb ? deg1 : deg0;
    const int* order_k = order_all + kb * N_EDGES;
    const int* keys_k  = keys_all + kb * N_EDGES;
    const unsigned short* WT = kb ? WT1 : WT0;
    const float* bias = kb ? bias1 : bias0;
    const float* eps  = kb ? eps1 : eps0;

    int tid = threadIdx.x;
    int w = tid >> 6, ln = tid & 63, l15 = ln & 15;
    int e0 = bx * 64;
    bias_lds[tid] = bias[tid];
    if (tid < 64) {
        int s = e0 + tid;
        tgt[tid] = (s < N_EDGES) ? keys_k[s] : -1;
    }

    int sA = e0 + w * 16 + (ln >> 2);
    if (sA >= N_EDGES) sA = N_EDGES - 1;
    int eA = order_k[sA];
    int p0 = pairs[eA];
    int p1 = pairs[N_EDGES + eA];
    int qs = (ln & 3) ^ ((ln >> 3) & 3);
    const unsigned short* a0src = hbf + (size_t)p0 * DIN_ + qs * 8;
    const unsigned short* a1src = hbf + (size_t)p1 * DIN_ + qs * 8;
    int brow = w * 64;
    int swz = ((ln >> 4) ^ ((l15 >> 1) & 3)) * 8;

    int r8 = tid >> 2, q8 = tid & 3;
    int m8 = (q8 ^ ((r8 >> 1) & 3)) * 8;
    int s8 = e0 + r8;
    if (s8 >= N_EDGES) s8 = N_EDGES - 1;
    int e8 = order_k[s8];

    f32x4 acc0[16], acc1[16];
#pragma unroll
    for (int j = 0; j < 16; ++j) { acc0[j] = (f32x4)(0.f); acc1[j] = (f32x4)(0.f); }

    // ---- staging helpers (6 vmem issues per step per wave) ----
    // kk < 8:  4x B + 2x A (gathered h rows)
    // kk == 8: 2x degrees reg-loads (issued FIRST -> compiler auto-wait = vmcnt(4)) + 4x B
    auto stage = [&](int kk, int b) {
        if (kk < 8) {
            gl_lds16(a0src + kk * 32, &Alds[b][0][w * 16][0]);
            gl_lds16(a1src + kk * 32, &Alds[b][1][w * 16][0]);
#pragma unroll
            for (int i = 0; i < 4; ++i) {
                int n = brow + i * 16 + (ln >> 2);
                gl_lds16(WT + (size_t)n * KF_ + kk * 32 + qs * 8,
                         &Blds[b][brow + i * 16][0]);
            }
        } else {
            float4 da[2], db[2];
#pragma unroll
            for (int t = 0; t < 2; ++t) {
                da[t] = make_float4(0.f, 0.f, 0.f, 0.f);
                db[t] = da[t];
                if (q8 < 2) {
                    const float4* s4 = (const float4*)(degrees +
                        ((size_t)t * N_EDGES + e8) * OH_ + q8 * 8);
                    da[t] = s4[0]; db[t] = s4[1];
                }
            }
#pragma unroll
            for (int i = 0; i < 4; ++i) {
                int n = brow + i * 16 + (ln >> 2);
                gl_lds16(WT + (size_t)n * KF_ + 8 * 32 + qs * 8,
                         &Blds[b][brow + i * 16][0]);
            }
#pragma unroll
            for (int t = 0; t < 2; ++t) {
                uint4 v = pack8(da[t].x, da[t].y, da[t].z, da[t].w,
                                db[t].x, db[t].y, db[t].z, db[t].w);
                if (q8 >= 2) v = make_uint4(0u, 0u, 0u, 0u);
                *(uint4*)&Alds[b][t][r8][m8] = v;
            }
        }
    };

    stage(0, 0);
    int buf = 0;
    for (int kk = 0; kk < 9; ++kk) {
        if (kk < 8) {
            stage(kk + 1, buf ^ 1);
            wait_vm6_barrier();   // cur-step loads landed; next-step 6 stay in flight
        } else {
            wait_vm0_barrier();
        }
        short8 a0f = *(const short8*)&Alds[buf][0][w * 16 + l15][swz];
        short8 a1f = *(const short8*)&Alds[buf][1][w * 16 + l15][swz];
#pragma unroll
        for (int j = 0; j < 16; ++j) {
            short8 bf = *(const short8*)&Blds[buf][j * 16 + l15][swz];
            acc0[j] = __builtin_amdgcn_mfma_f32_16x16x32_bf16(a0f, bf, acc0[j], 0, 0, 0);
            acc1[j] = __builtin_amdgcn_mfma_f32_16x16x32_bf16(a1f, bf, acc1[j], 0, 0, 0);
        }
        wait_lgkm_barrier();      // ds reads done -> safe to overwrite other buffer
        buf ^= 1;
    }

    // ---- epilogue: sigmoid product -> LDS chunk -> segmented reduce (atomic flush) ----
    float* red = (float*)&Blds[0][0][0];   // [64][68]
    float epv = 1.0f + eps[0];
    int rloc = w * 16 + ((ln >> 4) << 2);
    int c = tid & 63, Rb = (tid >> 6) * 16;

#pragma unroll
    for (int jc = 0; jc < 4; ++jc) {
#pragma unroll
        for (int jj = 0; jj < 4; ++jj) {
            float bv = bias_lds[(jc * 4 + jj) * 16 + l15];
#pragma unroll
            for (int i = 0; i < 4; ++i) {
                int row = rloc + i;
                float v = 0.f;
                if (e0 + row < N_EDGES) {
                    float a = acc0[jc * 4 + jj][i] + bv;
                    float b = acc1[jc * 4 + jj][i] + bv;
                    float ea = __expf(-a), eb = __expf(-b);
                    v = epv * fast_rcp((1.f + ea) * (1.f + eb));
                }
                red[row * 68 + jj * 16 + l15] = v;
            }
        }
        __syncthreads();
        int n = jc * 64 + c;
        int runkey = tgt[Rb];
        float runsum = red[Rb * 68 + c];
        for (int r = Rb + 1; r < Rb + 16; ++r) {
            int k = tgt[r];
            float val = red[r * 68 + c];
            if (k != runkey) {
                if (runkey >= 0) atomicAdd(&out[(size_t)runkey * DOUT_ + n], runsum);
                runkey = k;
                runsum = val;
            } else {
                runsum += val;
            }
        }
        if (runkey >= 0) atomicAdd(&out[(size_t)runkey * DOUT_ + n], runsum);
        __syncthreads();
    }
}

extern "C" void kernel_launch(void* const* d_in, const int* in_sizes, int n_in,
                              void* d_out, int out_size, void* d_ws, size_t ws_size,
                              hipStream_t stream) {
    const float* h        = (const float*)d_in[0];
    const int*   pairs_k0 = (const int*)d_in[1];
    const int*   pairs_k1 = (const int*)d_in[2];
    const float* deg_k0   = (const float*)d_in[3];
    const float* deg_k1   = (const float*)d_in[4];
    const int*   sc_k0    = (const int*)d_in[5];
    const int*   sc_k1    = (const int*)d_in[6];
    const float* W_lin    = (const float*)d_in[7];
    const float* b_lin    = (const float*)d_in[8];
    const float* W_k0     = (const float*)d_in[9];
    const float* b_k0     = (const float*)d_in[10];
    const float* W_k1     = (const float*)d_in[11];
    const float* b_k1     = (const float*)d_in[12];
    const float* eps_k0   = (const float*)d_in[13];
    const float* eps_k1   = (const float*)d_in[14];
    float* out = (float*)d_out;

    size_t ush_elems = (size_t)DOUT_ * DIN_ + 2 * (size_t)DOUT_ * KF_ + (size_t)N_NODES * DIN_;
    size_t int_elems = 2 * (size_t)N_NODES * 2 + 2 * (size_t)N_EDGES * 2 + 512;
    size_t need = ush_elems * sizeof(unsigned short) + int_elems * sizeof(int);
    if (ws_size < need) return;  // fail loudly in validation

    unsigned short* WT_lin = (unsigned short*)d_ws;
    unsigned short* WT_k0  = WT_lin + DOUT_ * DIN_;
    unsigned short* WT_k1  = WT_k0 + DOUT_ * KF_;
    unsigned short* h_bf   = WT_k1 + DOUT_ * KF_;
    int* hist     = (int*)(h_bf + (size_t)N_NODES * DIN_);
    int* offs     = hist + 2 * N_NODES;
    int* order    = offs + 2 * N_NODES;     // [2*E]
    int* keys     = order + 2 * N_EDGES;    // [2*E]
    int* partials = keys + 2 * N_EDGES;     // [512]

    hipMemsetAsync(hist, 0, 2 * N_NODES * sizeof(int), stream);
    hist_kernel<<<(N_EDGES + 255) / 256, 256, 0, stream>>>(sc_k0, sc_k1, hist);
    scan_pass1<<<SCAN_NB, 256, 0, stream>>>(hist, partials);
    scan_pass2<<<1, 512, 0, stream>>>(partials);
    scan_pass3<<<SCAN_NB, 256, 0, stream>>>(hist, partials, offs);
    rank_kernel<<<(N_EDGES + 255) / 256, 256, 0, stream>>>(sc_k0, sc_k1, offs, order, keys);

    prep_weights<<<(DOUT_ * KF_ + 255) / 256, 256, 0, stream>>>(W_lin, W_k0, W_k1,
                                                                WT_lin, WT_k0, WT_k1);
    conv_h<<<(N_NODES * DIN_ / 8) / 256, 256, 0, stream>>>(h, h_bf);
    main_gemm<<<(N_NODES + 63) / 64, 256, 0, stream>>>(h_bf, WT_lin, b_lin, out);
    edge_gemm<<<2 * NBLK_EDGE, 256, 0, stream>>>(h_bf, pairs_k0, pairs_k1, deg_k0, deg_k1,
                                                 order, keys, WT_k0, WT_k1, b_k0, b_k1,
                                                 eps_k0, eps_k1, out);
}

// Round 6
// 427.116 us; speedup vs baseline: 1.7391x; 1.7391x over previous
//
#include <hip/hip_runtime.h>
#include <hip/hip_bf16.h>

#define N_NODES 50000
#define N_EDGES 250000
#define DIN_ 256
#define DOUT_ 256
#define OH_ 16
#define KF_ 288   // 256 (h) + 16 (degrees) + 16 zero-pad
#define NBLK_EDGE ((N_EDGES + 63) / 64)     // 3907
#define NBLK_G ((N_NODES + 63) / 64)        // 782
#define SCAN_TOT (2 * N_NODES)              // 100000
#define SCAN_NB ((SCAN_TOT + 255) / 256)    // 391

typedef short short8 __attribute__((ext_vector_type(8)));
typedef float f32x4 __attribute__((ext_vector_type(4)));

__device__ __forceinline__ unsigned short f2bf(float f) {
    unsigned u = __builtin_bit_cast(unsigned, f);
    return (unsigned short)((u + 0x7fffu + ((u >> 16) & 1u)) >> 16);
}

__device__ __forceinline__ float bf2f(unsigned short v) {
    return __builtin_bit_cast(float, (unsigned)v << 16);
}

__device__ __forceinline__ uint4 pack8(float f0, float f1, float f2, float f3,
                                       float f4, float f5, float f6, float f7) {
    uint4 u;
    u.x = (unsigned)f2bf(f0) | ((unsigned)f2bf(f1) << 16);
    u.y = (unsigned)f2bf(f2) | ((unsigned)f2bf(f3) << 16);
    u.z = (unsigned)f2bf(f4) | ((unsigned)f2bf(f5) << 16);
    u.w = (unsigned)f2bf(f6) | ((unsigned)f2bf(f7) << 16);
    return u;
}

__device__ __forceinline__ float fast_rcp(float x) {
#if __has_builtin(__builtin_amdgcn_rcpf)
    return __builtin_amdgcn_rcpf(x);
#else
    return 1.0f / x;
#endif
}

// async global -> LDS, 16 bytes per lane (dest = wave-uniform base + lane*16)
__device__ __forceinline__ void gl_lds16(const void* g, void* l) {
    __builtin_amdgcn_global_load_lds(
        (const __attribute__((address_space(1))) unsigned int*)g,
        (__attribute__((address_space(3))) unsigned int*)l, 16, 0, 0);
}

// ---------- sort pipeline: counting sort of edges by scatter target ----------
__global__ void hist_kernel(const int* __restrict__ sc0, const int* __restrict__ sc1,
                            int* __restrict__ hist) {
    int e = blockIdx.x * 256 + threadIdx.x;
    if (e < N_EDGES) {
        atomicAdd(&hist[sc0[e]], 1);
        atomicAdd(&hist[N_NODES + sc1[e]], 1);
    }
}

__global__ void scan_pass1(const int* __restrict__ hist, int* __restrict__ partials) {
    __shared__ int sdata[256];
    int gid = blockIdx.x * 256 + threadIdx.x;
    sdata[threadIdx.x] = (gid < SCAN_TOT) ? hist[gid] : 0;
    __syncthreads();
    for (int d = 128; d > 0; d >>= 1) {
        if (threadIdx.x < d) sdata[threadIdx.x] += sdata[threadIdx.x + d];
        __syncthreads();
    }
    if (threadIdx.x == 0) partials[blockIdx.x] = sdata[0];
}

__global__ __launch_bounds__(512) void scan_pass2(int* __restrict__ partials) {
    __shared__ int s[512];
    int t = threadIdx.x;
    s[t] = (t < SCAN_NB) ? partials[t] : 0;
    __syncthreads();
    for (int d = 1; d < 512; d <<= 1) {
        int add = (t >= d) ? s[t - d] : 0;
        __syncthreads();
        s[t] += add;
        __syncthreads();
    }
    if (t < SCAN_NB) partials[t] = (t == 0) ? 0 : s[t - 1];   // exclusive
}

__global__ void scan_pass3(const int* __restrict__ hist, const int* __restrict__ partials,
                           int* __restrict__ offs) {
    __shared__ int s[256];
    int gid = blockIdx.x * 256 + threadIdx.x;
    int t = threadIdx.x;
    int v = (gid < SCAN_TOT) ? hist[gid] : 0;
    s[t] = v;
    __syncthreads();
    for (int d = 1; d < 256; d <<= 1) {
        int add = (t >= d) ? s[t - d] : 0;
        __syncthreads();
        s[t] += add;
        __syncthreads();
    }
    if (gid < SCAN_TOT) offs[gid] = partials[blockIdx.x] + s[t] - v;  // exclusive
}

__global__ void rank_kernel(const int* __restrict__ sc0, const int* __restrict__ sc1,
                            int* __restrict__ offs, int* __restrict__ order,
                            int* __restrict__ keys) {
    int e = blockIdx.x * 256 + threadIdx.x;
    if (e < N_EDGES) {
        int k0 = sc0[e];
        int p = atomicAdd(&offs[k0], 1);
        order[p] = e; keys[p] = k0;
        int k1 = sc1[e];
        int q = atomicAdd(&offs[N_NODES + k1], 1);
        order[q] = e; keys[q] = k1;
    }
}

// ---------- weight / input prep ----------
__global__ void prep_weights(const float* __restrict__ W_lin,
                             const float* __restrict__ W_k0,
                             const float* __restrict__ W_k1,
                             unsigned short* __restrict__ WT_lin,
                             unsigned short* __restrict__ WT_k0,
                             unsigned short* __restrict__ WT_k1) {
    int idx = blockIdx.x * 256 + threadIdx.x;
    if (idx < DOUT_ * DIN_) {
        int n = idx >> 8, k = idx & 255;
        WT_lin[idx] = f2bf(W_lin[k * DOUT_ + n]);
    }
    if (idx < DOUT_ * KF_) {
        int n = idx / KF_, k = idx - n * KF_;
        float v0 = 0.f, v1 = 0.f;
        if (k < DIN_ + OH_) {
            v0 = W_k0[k * DOUT_ + n];
            v1 = W_k1[k * DOUT_ + n];
        }
        WT_k0[idx] = f2bf(v0);
        WT_k1[idx] = f2bf(v1);
    }
}

__global__ void conv_h(const float* __restrict__ h, unsigned short* __restrict__ hbf) {
    int idx = blockIdx.x * 256 + threadIdx.x;
    const float4* s = (const float4*)(h + (size_t)idx * 8);
    float4 a = s[0], b = s[1];
    ((uint4*)hbf)[idx] = pack8(a.x, a.y, a.z, a.w, b.x, b.y, b.z, b.w);
}

// h3 = h @ W_lin + b_lin   (writes all of d_out, f32)
__global__ __launch_bounds__(256) void main_gemm(const unsigned short* __restrict__ hbf,
                                                 const unsigned short* __restrict__ WT,
                                                 const float* __restrict__ bias,
                                                 float* __restrict__ out) {
    __shared__ unsigned short Alds[2][64][32];
    __shared__ unsigned short Blds[2][256][32];
    __shared__ float bias_lds[256];
    int tid = threadIdx.x;
    int w = tid >> 6, ln = tid & 63, l15 = ln & 15;
    int row0 = blockIdx.x * 64;
    bias_lds[tid] = bias[tid];

    int ar = row0 + w * 16 + (ln >> 2);
    if (ar >= N_NODES) ar = N_NODES - 1;
    int qs = (ln & 3) ^ ((ln >> 3) & 3);
    const unsigned short* asrc = hbf + (size_t)ar * DIN_ + qs * 8;
    int brow = w * 64;
    int swz = ((ln >> 4) ^ ((l15 >> 1) & 3)) * 8;

    f32x4 acc[16];
#pragma unroll
    for (int j = 0; j < 16; ++j) acc[j] = (f32x4)(0.f);

    gl_lds16(asrc, &Alds[0][w * 16][0]);
#pragma unroll
    for (int i = 0; i < 4; ++i) {
        int n = brow + i * 16 + (ln >> 2);
        gl_lds16(WT + (size_t)n * DIN_ + qs * 8, &Blds[0][brow + i * 16][0]);
    }
    __syncthreads();

    int buf = 0;
    for (int kk = 0; kk < 8; ++kk) {
        if (kk < 7) {
            gl_lds16(asrc + (kk + 1) * 32, &Alds[buf ^ 1][w * 16][0]);
#pragma unroll
            for (int i = 0; i < 4; ++i) {
                int n = brow + i * 16 + (ln >> 2);
                gl_lds16(WT + (size_t)n * DIN_ + (kk + 1) * 32 + qs * 8,
                         &Blds[buf ^ 1][brow + i * 16][0]);
            }
        }
        short8 af = *(const short8*)&Alds[buf][w * 16 + l15][swz];
#pragma unroll
        for (int j = 0; j < 16; ++j) {
            short8 bf = *(const short8*)&Blds[buf][j * 16 + l15][swz];
            acc[j] = __builtin_amdgcn_mfma_f32_16x16x32_bf16(af, bf, acc[j], 0, 0, 0);
        }
        __syncthreads();
        buf ^= 1;
    }

    int rbase = row0 + w * 16 + ((ln >> 4) << 2);
#pragma unroll
    for (int j = 0; j < 16; ++j) {
        int n = j * 16 + l15;
        float bv = bias_lds[n];
#pragma unroll
        for (int i = 0; i < 4; ++i) {
            int rr = rbase + i;
            if (rr < N_NODES) out[(size_t)rr * DOUT_ + n] = acc[j][i] + bv;
        }
    }
}

// G_key = h @ W_key[:256,:] + b_key  -> bf16 [N][256]; both keys in one launch
__global__ __launch_bounds__(256) void g_gemm(const unsigned short* __restrict__ hbf,
                                              const unsigned short* __restrict__ WT0,
                                              const unsigned short* __restrict__ WT1,
                                              const float* __restrict__ b0,
                                              const float* __restrict__ b1,
                                              unsigned short* __restrict__ G0,
                                              unsigned short* __restrict__ G1) {
    __shared__ unsigned short Alds[2][64][32];
    __shared__ unsigned short Blds[2][256][32];
    __shared__ float bias_lds[256];
    int kb = (blockIdx.x >= NBLK_G) ? 1 : 0;
    int bx = blockIdx.x - kb * NBLK_G;
    const unsigned short* WT = kb ? WT1 : WT0;
    const float* bias = kb ? b1 : b0;
    unsigned short* G = kb ? G1 : G0;

    int tid = threadIdx.x;
    int w = tid >> 6, ln = tid & 63, l15 = ln & 15;
    int row0 = bx * 64;
    bias_lds[tid] = bias[tid];

    int ar = row0 + w * 16 + (ln >> 2);
    if (ar >= N_NODES) ar = N_NODES - 1;
    int qs = (ln & 3) ^ ((ln >> 3) & 3);
    const unsigned short* asrc = hbf + (size_t)ar * DIN_ + qs * 8;
    int brow = w * 64;
    int swz = ((ln >> 4) ^ ((l15 >> 1) & 3)) * 8;

    f32x4 acc[16];
#pragma unroll
    for (int j = 0; j < 16; ++j) acc[j] = (f32x4)(0.f);

    gl_lds16(asrc, &Alds[0][w * 16][0]);
#pragma unroll
    for (int i = 0; i < 4; ++i) {
        int n = brow + i * 16 + (ln >> 2);
        gl_lds16(WT + (size_t)n * KF_ + qs * 8, &Blds[0][brow + i * 16][0]);
    }
    __syncthreads();

    int buf = 0;
    for (int kk = 0; kk < 8; ++kk) {
        if (kk < 7) {
            gl_lds16(asrc + (kk + 1) * 32, &Alds[buf ^ 1][w * 16][0]);
#pragma unroll
            for (int i = 0; i < 4; ++i) {
                int n = brow + i * 16 + (ln >> 2);
                gl_lds16(WT + (size_t)n * KF_ + (kk + 1) * 32 + qs * 8,
                         &Blds[buf ^ 1][brow + i * 16][0]);
            }
        }
        short8 af = *(const short8*)&Alds[buf][w * 16 + l15][swz];
#pragma unroll
        for (int j = 0; j < 16; ++j) {
            short8 bf = *(const short8*)&Blds[buf][j * 16 + l15][swz];
            acc[j] = __builtin_amdgcn_mfma_f32_16x16x32_bf16(af, bf, acc[j], 0, 0, 0);
        }
        __syncthreads();
        buf ^= 1;
    }

    int rbase = row0 + w * 16 + ((ln >> 4) << 2);
#pragma unroll
    for (int j = 0; j < 16; ++j) {
        int n = j * 16 + l15;
        float bv = bias_lds[n];
#pragma unroll
        for (int i = 0; i < 4; ++i) {
            int rr = rbase + i;
            if (rr < N_NODES) G[(size_t)rr * DOUT_ + n] = f2bf(acc[j][i] + bv);
        }
    }
}

// Fused edge epilogue: D = deg@W_d (one MFMA step), logit = G[pair] + D,
// out[key] += epv * sigmoid(logit0)*sigmoid(logit1), segment-summed (sorted order).
__global__ __launch_bounds__(256) void edge_fused(const unsigned short* __restrict__ Gk0,
                                                  const unsigned short* __restrict__ Gk1,
                                                  const int* __restrict__ pairs0,
                                                  const int* __restrict__ pairs1,
                                                  const float* __restrict__ deg0,
                                                  const float* __restrict__ deg1,
                                                  const int* __restrict__ order_all,
                                                  const int* __restrict__ keys_all,
                                                  const unsigned short* __restrict__ WT0,
                                                  const unsigned short* __restrict__ WT1,
                                                  const float* __restrict__ eps0,
                                                  const float* __restrict__ eps1,
                                                  float* __restrict__ out) {
    __shared__ float red0[64][68];   // 17.4 KB
    __shared__ float red1[64][68];   // 17.4 KB
    __shared__ int tgt[64], pl0[64], pl1[64], el[64];
    int kb = (blockIdx.x >= NBLK_EDGE) ? 1 : 0;
    int bx = blockIdx.x - kb * NBLK_EDGE;
    const unsigned short* G = kb ? Gk1 : Gk0;
    const int* pairs = kb ? pairs1 : pairs0;
    const float* degrees = kb ? deg1 : deg0;
    const int* order_k = order_all + kb * N_EDGES;
    const int* keys_k  = keys_all + kb * N_EDGES;
    const unsigned short* WT = kb ? WT1 : WT0;
    float epv = 1.0f + (kb ? eps1[0] : eps0[0]);

    int tid = threadIdx.x;
    int w = tid >> 6, ln = tid & 63, l15 = ln & 15, ks = ln >> 4;
    int e0 = bx * 64;
    if (tid < 64) {
        int s = e0 + tid;
        int sc = (s < N_EDGES) ? s : N_EDGES - 1;
        int e = order_k[sc];
        el[tid]  = e;
        tgt[tid] = (s < N_EDGES) ? keys_k[s] : -1;
        pl0[tid] = pairs[e];
        pl1[tid] = pairs[N_EDGES + e];
    }
    __syncthreads();

    // A fragments from degrees, K=32 (k<16 real, rest zero). A row = w*16+l15.
    int eA = el[w * 16 + l15];
    short8 a0f = (short8)0, a1f = (short8)0;
    if (ks < 2) {
        const float4* s0 = (const float4*)(degrees + ((size_t)0 * N_EDGES + eA) * OH_ + ks * 8);
        const float4* s1 = (const float4*)(degrees + ((size_t)1 * N_EDGES + eA) * OH_ + ks * 8);
        float4 xa = s0[0], xb = s0[1];
        float4 ya = s1[0], yb = s1[1];
        a0f = __builtin_bit_cast(short8, pack8(xa.x, xa.y, xa.z, xa.w, xb.x, xb.y, xb.z, xb.w));
        a1f = __builtin_bit_cast(short8, pack8(ya.x, ya.y, ya.z, ya.w, yb.x, yb.y, yb.z, yb.w));
    }

    int c = ln;            // reducer column (0..63)
    int Rb = w * 16;       // reducer row base

#pragma unroll
    for (int half = 0; half < 2; ++half) {
        f32x4 acc0[8], acc1[8];
#pragma unroll
        for (int j = 0; j < 8; ++j) { acc0[j] = (f32x4)(0.f); acc1[j] = (f32x4)(0.f); }
#pragma unroll
        for (int j = 0; j < 8; ++j) {
            int n = half * 128 + j * 16 + l15;
            short8 bf = (short8)0;
            if (ks < 2) bf = *(const short8*)(WT + (size_t)n * KF_ + 256 + ks * 8);
            acc0[j] = __builtin_amdgcn_mfma_f32_16x16x32_bf16(a0f, bf, acc0[j], 0, 0, 0);
            acc1[j] = __builtin_amdgcn_mfma_f32_16x16x32_bf16(a1f, bf, acc1[j], 0, 0, 0);
        }
#pragma unroll
        for (int jc = 0; jc < 2; ++jc) {
            // D -> red (C layout: row = w*16 + ks*4 + i, col = jj*16 + l15)
#pragma unroll
            for (int jj = 0; jj < 4; ++jj) {
#pragma unroll
                for (int i = 0; i < 4; ++i) {
                    int row = w * 16 + ks * 4 + i;
                    red0[row][jj * 16 + l15] = acc0[jc * 4 + jj][i];
                    red1[row][jj * 16 + l15] = acc1[jc * 4 + jj][i];
                }
            }
            __syncthreads();
            int n = half * 128 + jc * 64 + c;
            int runkey = tgt[Rb];
            float runsum;
            {
                float g0 = bf2f(G[(size_t)pl0[Rb] * DOUT_ + n]);
                float g1 = bf2f(G[(size_t)pl1[Rb] * DOUT_ + n]);
                float ea = __expf(-(g0 + red0[Rb][c]));
                float eb = __expf(-(g1 + red1[Rb][c]));
                runsum = epv * fast_rcp((1.f + ea) * (1.f + eb));
            }
#pragma unroll
            for (int rr = 1; rr < 16; ++rr) {
                int r = Rb + rr;
                float g0 = bf2f(G[(size_t)pl0[r] * DOUT_ + n]);
                float g1 = bf2f(G[(size_t)pl1[r] * DOUT_ + n]);
                float ea = __expf(-(g0 + red0[r][c]));
                float eb = __expf(-(g1 + red1[r][c]));
                float val = epv * fast_rcp((1.f + ea) * (1.f + eb));
                int k = tgt[r];
                if (k != runkey) {
                    if (runkey >= 0) atomicAdd(&out[(size_t)runkey * DOUT_ + n], runsum);
                    runkey = k;
                    runsum = val;
                } else {
                    runsum += val;
                }
            }
            if (runkey >= 0) atomicAdd(&out[(size_t)runkey * DOUT_ + n], runsum);
            __syncthreads();
        }
    }
}

extern "C" void kernel_launch(void* const* d_in, const int* in_sizes, int n_in,
                              void* d_out, int out_size, void* d_ws, size_t ws_size,
                              hipStream_t stream) {
    const float* h        = (const float*)d_in[0];
    const int*   pairs_k0 = (const int*)d_in[1];
    const int*   pairs_k1 = (const int*)d_in[2];
    const float* deg_k0   = (const float*)d_in[3];
    const float* deg_k1   = (const float*)d_in[4];
    const int*   sc_k0    = (const int*)d_in[5];
    const int*   sc_k1    = (const int*)d_in[6];
    const float* W_lin    = (const float*)d_in[7];
    const float* b_lin    = (const float*)d_in[8];
    const float* W_k0     = (const float*)d_in[9];
    const float* b_k0     = (const float*)d_in[10];
    const float* W_k1     = (const float*)d_in[11];
    const float* b_k1     = (const float*)d_in[12];
    const float* eps_k0   = (const float*)d_in[13];
    const float* eps_k1   = (const float*)d_in[14];
    float* out = (float*)d_out;

    size_t ush_elems = (size_t)DOUT_ * DIN_ + 2 * (size_t)DOUT_ * KF_
                     + 3 * (size_t)N_NODES * DIN_;          // h_bf + G0 + G1
    size_t int_elems = 2 * (size_t)N_NODES * 2 + 2 * (size_t)N_EDGES * 2 + 512;
    size_t need = ush_elems * sizeof(unsigned short) + int_elems * sizeof(int);
    if (ws_size < need) return;  // fail loudly in validation

    unsigned short* WT_lin = (unsigned short*)d_ws;
    unsigned short* WT_k0  = WT_lin + DOUT_ * DIN_;
    unsigned short* WT_k1  = WT_k0 + DOUT_ * KF_;
    unsigned short* h_bf   = WT_k1 + DOUT_ * KF_;
    unsigned short* G0     = h_bf + (size_t)N_NODES * DIN_;
    unsigned short* G1     = G0 + (size_t)N_NODES * DIN_;
    int* hist     = (int*)(G1 + (size_t)N_NODES * DIN_);
    int* offs     = hist + 2 * N_NODES;
    int* order    = offs + 2 * N_NODES;     // [2*E]
    int* keys     = order + 2 * N_EDGES;    // [2*E]
    int* partials = keys + 2 * N_EDGES;     // [512]

    hipMemsetAsync(hist, 0, 2 * N_NODES * sizeof(int), stream);
    hist_kernel<<<(N_EDGES + 255) / 256, 256, 0, stream>>>(sc_k0, sc_k1, hist);
    scan_pass1<<<SCAN_NB, 256, 0, stream>>>(hist, partials);
    scan_pass2<<<1, 512, 0, stream>>>(partials);
    scan_pass3<<<SCAN_NB, 256, 0, stream>>>(hist, partials, offs);
    rank_kernel<<<(N_EDGES + 255) / 256, 256, 0, stream>>>(sc_k0, sc_k1, offs, order, keys);

    prep_weights<<<(DOUT_ * KF_ + 255) / 256, 256, 0, stream>>>(W_lin, W_k0, W_k1,
                                                                WT_lin, WT_k0, WT_k1);
    conv_h<<<(N_NODES * DIN_ / 8) / 256, 256, 0, stream>>>(h, h_bf);
    main_gemm<<<NBLK_G, 256, 0, stream>>>(h_bf, WT_lin, b_lin, out);
    g_gemm<<<2 * NBLK_G, 256, 0, stream>>>(h_bf, WT_k0, WT_k1, b_k0, b_k1, G0, G1);
    edge_fused<<<2 * NBLK_EDGE, 256, 0, stream>>>(G0, G1, pairs_k0, pairs_k1,
                                                  deg_k0, deg_k1, order, keys,
                                                  WT_k0, WT_k1, eps_k0, eps_k1, out);
}

// Round 7
// 373.691 us; speedup vs baseline: 1.9877x; 1.1430x over previous
//
#include <hip/hip_runtime.h>
#include <hip/hip_bf16.h>

#define N_NODES 50000
#define N_EDGES 250000
#define DIN_ 256
#define DOUT_ 256
#define OH_ 16
#define KF_ 288   // 256 (h) + 16 (degrees) + 16 zero-pad
#define NBLK_EDGE ((N_EDGES + 63) / 64)     // 3907
#define NBLK_G ((N_NODES + 63) / 64)        // 782
#define SCAN_TOT (2 * N_NODES)              // 100000
#define SCAN_NB ((SCAN_TOT + 255) / 256)    // 391

typedef short short8 __attribute__((ext_vector_type(8)));
typedef float f32x4 __attribute__((ext_vector_type(4)));

__device__ __forceinline__ unsigned short f2bf(float f) {
    unsigned u = __builtin_bit_cast(unsigned, f);
    return (unsigned short)((u + 0x7fffu + ((u >> 16) & 1u)) >> 16);
}

__device__ __forceinline__ float bf2f(unsigned v) {
    return __builtin_bit_cast(float, v << 16);
}

__device__ __forceinline__ uint4 pack8(float f0, float f1, float f2, float f3,
                                       float f4, float f5, float f6, float f7) {
    uint4 u;
    u.x = (unsigned)f2bf(f0) | ((unsigned)f2bf(f1) << 16);
    u.y = (unsigned)f2bf(f2) | ((unsigned)f2bf(f3) << 16);
    u.z = (unsigned)f2bf(f4) | ((unsigned)f2bf(f5) << 16);
    u.w = (unsigned)f2bf(f6) | ((unsigned)f2bf(f7) << 16);
    return u;
}

__device__ __forceinline__ float fast_rcp(float x) {
#if __has_builtin(__builtin_amdgcn_rcpf)
    return __builtin_amdgcn_rcpf(x);
#else
    return 1.0f / x;
#endif
}

// async global -> LDS, 16 bytes per lane (dest = wave-uniform base + lane*16)
__device__ __forceinline__ void gl_lds16(const void* g, void* l) {
    __builtin_amdgcn_global_load_lds(
        (const __attribute__((address_space(1))) unsigned int*)g,
        (__attribute__((address_space(3))) unsigned int*)l, 16, 0, 0);
}

// ---------- sort pipeline: counting sort of edges by scatter target ----------
__global__ void hist_kernel(const int* __restrict__ sc0, const int* __restrict__ sc1,
                            int* __restrict__ hist) {
    int e = blockIdx.x * 256 + threadIdx.x;
    if (e < N_EDGES) {
        atomicAdd(&hist[sc0[e]], 1);
        atomicAdd(&hist[N_NODES + sc1[e]], 1);
    }
}

__global__ void scan_pass1(const int* __restrict__ hist, int* __restrict__ partials) {
    __shared__ int sdata[256];
    int gid = blockIdx.x * 256 + threadIdx.x;
    sdata[threadIdx.x] = (gid < SCAN_TOT) ? hist[gid] : 0;
    __syncthreads();
    for (int d = 128; d > 0; d >>= 1) {
        if (threadIdx.x < d) sdata[threadIdx.x] += sdata[threadIdx.x + d];
        __syncthreads();
    }
    if (threadIdx.x == 0) partials[blockIdx.x] = sdata[0];
}

__global__ __launch_bounds__(512) void scan_pass2(int* __restrict__ partials) {
    __shared__ int s[512];
    int t = threadIdx.x;
    s[t] = (t < SCAN_NB) ? partials[t] : 0;
    __syncthreads();
    for (int d = 1; d < 512; d <<= 1) {
        int add = (t >= d) ? s[t - d] : 0;
        __syncthreads();
        s[t] += add;
        __syncthreads();
    }
    if (t < SCAN_NB) partials[t] = (t == 0) ? 0 : s[t - 1];   // exclusive
}

__global__ void scan_pass3(const int* __restrict__ hist, const int* __restrict__ partials,
                           int* __restrict__ offs) {
    __shared__ int s[256];
    int gid = blockIdx.x * 256 + threadIdx.x;
    int t = threadIdx.x;
    int v = (gid < SCAN_TOT) ? hist[gid] : 0;
    s[t] = v;
    __syncthreads();
    for (int d = 1; d < 256; d <<= 1) {
        int add = (t >= d) ? s[t - d] : 0;
        __syncthreads();
        s[t] += add;
        __syncthreads();
    }
    if (gid < SCAN_TOT) offs[gid] = partials[blockIdx.x] + s[t] - v;  // exclusive
}

__global__ void rank_kernel(const int* __restrict__ sc0, const int* __restrict__ sc1,
                            int* __restrict__ offs, int* __restrict__ order,
                            int* __restrict__ keys) {
    int e = blockIdx.x * 256 + threadIdx.x;
    if (e < N_EDGES) {
        int k0 = sc0[e];
        int p = atomicAdd(&offs[k0], 1);
        order[p] = e; keys[p] = k0;
        int k1 = sc1[e];
        int q = atomicAdd(&offs[N_NODES + k1], 1);
        order[q] = e; keys[q] = k1;
    }
}

// ---------- weight / input prep ----------
__global__ void prep_weights(const float* __restrict__ W_lin,
                             const float* __restrict__ W_k0,
                             const float* __restrict__ W_k1,
                             unsigned short* __restrict__ WT_lin,
                             unsigned short* __restrict__ WT_k0,
                             unsigned short* __restrict__ WT_k1) {
    int idx = blockIdx.x * 256 + threadIdx.x;
    if (idx < DOUT_ * DIN_) {
        int n = idx >> 8, k = idx & 255;
        WT_lin[idx] = f2bf(W_lin[k * DOUT_ + n]);
    }
    if (idx < DOUT_ * KF_) {
        int n = idx / KF_, k = idx - n * KF_;
        float v0 = 0.f, v1 = 0.f;
        if (k < DIN_ + OH_) {
            v0 = W_k0[k * DOUT_ + n];
            v1 = W_k1[k * DOUT_ + n];
        }
        WT_k0[idx] = f2bf(v0);
        WT_k1[idx] = f2bf(v1);
    }
}

__global__ void conv_h(const float* __restrict__ h, unsigned short* __restrict__ hbf) {
    int idx = blockIdx.x * 256 + threadIdx.x;
    const float4* s = (const float4*)(h + (size_t)idx * 8);
    float4 a = s[0], b = s[1];
    ((uint4*)hbf)[idx] = pack8(a.x, a.y, a.z, a.w, b.x, b.y, b.z, b.w);
}

// Three 50000x256x256 GEMMs in one launch:
//   kb=0: G0 = h@W_k0[:256]+b_k0 (bf16), kb=1: G1 likewise, kb=2: out = h@W_lin+b_lin (f32)
__global__ __launch_bounds__(256) void lin_gemms(const unsigned short* __restrict__ hbf,
                                                 const unsigned short* __restrict__ WT_lin,
                                                 const unsigned short* __restrict__ WTk0,
                                                 const unsigned short* __restrict__ WTk1,
                                                 const float* __restrict__ b_lin,
                                                 const float* __restrict__ bk0,
                                                 const float* __restrict__ bk1,
                                                 float* __restrict__ out,
                                                 unsigned short* __restrict__ G0,
                                                 unsigned short* __restrict__ G1) {
    __shared__ unsigned short Alds[2][64][32];
    __shared__ unsigned short Blds[2][256][32];
    __shared__ float bias_lds[256];
    int kb = blockIdx.x / NBLK_G;
    int bx = blockIdx.x - kb * NBLK_G;
    const unsigned short* WT; const float* bias; int stride;
    if (kb == 0)      { WT = WTk0;   bias = bk0;   stride = KF_; }
    else if (kb == 1) { WT = WTk1;   bias = bk1;   stride = KF_; }
    else              { WT = WT_lin; bias = b_lin; stride = DIN_; }

    int tid = threadIdx.x;
    int w = tid >> 6, ln = tid & 63, l15 = ln & 15;
    int row0 = bx * 64;
    bias_lds[tid] = bias[tid];

    int ar = row0 + w * 16 + (ln >> 2);
    if (ar >= N_NODES) ar = N_NODES - 1;
    int qs = (ln & 3) ^ ((ln >> 3) & 3);
    const unsigned short* asrc = hbf + (size_t)ar * DIN_ + qs * 8;
    int brow = w * 64;
    int swz = ((ln >> 4) ^ ((l15 >> 1) & 3)) * 8;

    f32x4 acc[16];
#pragma unroll
    for (int j = 0; j < 16; ++j) acc[j] = (f32x4)(0.f);

    gl_lds16(asrc, &Alds[0][w * 16][0]);
#pragma unroll
    for (int i = 0; i < 4; ++i) {
        int n = brow + i * 16 + (ln >> 2);
        gl_lds16(WT + (size_t)n * stride + qs * 8, &Blds[0][brow + i * 16][0]);
    }
    __syncthreads();

    int buf = 0;
    for (int kk = 0; kk < 8; ++kk) {
        if (kk < 7) {
            gl_lds16(asrc + (kk + 1) * 32, &Alds[buf ^ 1][w * 16][0]);
#pragma unroll
            for (int i = 0; i < 4; ++i) {
                int n = brow + i * 16 + (ln >> 2);
                gl_lds16(WT + (size_t)n * stride + (kk + 1) * 32 + qs * 8,
                         &Blds[buf ^ 1][brow + i * 16][0]);
            }
        }
        short8 af = *(const short8*)&Alds[buf][w * 16 + l15][swz];
#pragma unroll
        for (int j = 0; j < 16; ++j) {
            short8 bf = *(const short8*)&Blds[buf][j * 16 + l15][swz];
            acc[j] = __builtin_amdgcn_mfma_f32_16x16x32_bf16(af, bf, acc[j], 0, 0, 0);
        }
        __syncthreads();
        buf ^= 1;
    }

    int rbase = row0 + w * 16 + ((ln >> 4) << 2);
    unsigned short* G = (kb == 0) ? G0 : G1;
#pragma unroll
    for (int j = 0; j < 16; ++j) {
        int n = j * 16 + l15;
        float bv = bias_lds[n];
#pragma unroll
        for (int i = 0; i < 4; ++i) {
            int rr = rbase + i;
            if (rr < N_NODES) {
                float v = acc[j][i] + bv;
                if (kb == 2) out[(size_t)rr * DOUT_ + n] = v;
                else         G[(size_t)rr * DOUT_ + n] = f2bf(v);
            }
        }
    }
}

// Fused edge epilogue v2: thread owns 2 cols x 16 rows; all G gathers issued up-front
// (wave gather inst = 256B contiguous of one G row); 2 col-phases; D via one MFMA step
// staged bf16 in LDS; contiguous atomic flush via per-wave LDS transpose.
__global__ __launch_bounds__(256) void edge_fused(const unsigned short* __restrict__ Gk0,
                                                  const unsigned short* __restrict__ Gk1,
                                                  const int* __restrict__ pairs0,
                                                  const int* __restrict__ pairs1,
                                                  const float* __restrict__ deg0,
                                                  const float* __restrict__ deg1,
                                                  const int* __restrict__ order_all,
                                                  const int* __restrict__ keys_all,
                                                  const unsigned short* __restrict__ WT0,
                                                  const unsigned short* __restrict__ WT1,
                                                  const float* __restrict__ eps0,
                                                  const float* __restrict__ eps1,
                                                  float* __restrict__ out) {
    __shared__ unsigned short Dlds[2][64][132];   // 33.8 KB, D for one 128-col phase
    __shared__ float FL[4][64][2];                // 2 KB flush-transpose buffers
    __shared__ int tgt[64], pl0[64], pl1[64], el[64];
    int kb = (blockIdx.x >= NBLK_EDGE) ? 1 : 0;
    int bx = blockIdx.x - kb * NBLK_EDGE;
    const unsigned short* G = kb ? Gk1 : Gk0;
    const int* pairs = kb ? pairs1 : pairs0;
    const float* degrees = kb ? deg1 : deg0;
    const int* order_k = order_all + kb * N_EDGES;
    const int* keys_k  = keys_all + kb * N_EDGES;
    const unsigned short* WT = kb ? WT1 : WT0;
    float epv = 1.0f + (kb ? eps1[0] : eps0[0]);

    int tid = threadIdx.x;
    int w = tid >> 6, ln = tid & 63, l15 = ln & 15, ks = ln >> 4;
    int e0 = bx * 64;
    if (tid < 64) {
        int s = e0 + tid;
        int sc = (s < N_EDGES) ? s : N_EDGES - 1;
        int e = order_k[sc];
        el[tid]  = e;
        tgt[tid] = (s < N_EDGES) ? keys_k[s] : -1;
        pl0[tid] = pairs[e];
        pl1[tid] = pairs[N_EDGES + e];
    }
    __syncthreads();

    // ---- phase-0 gathers: cols [2ln, 2ln+1] of each of this wave's 16 G-row pairs ----
    unsigned int gv00[16], gv10[16];
#pragma unroll
    for (int r = 0; r < 16; ++r) {
        int row = w * 16 + r;
        gv00[r] = *(const unsigned int*)(G + (size_t)pl0[row] * DOUT_ + 2 * ln);
        gv10[r] = *(const unsigned int*)(G + (size_t)pl1[row] * DOUT_ + 2 * ln);
    }

    // ---- A-frags from degrees (K=32, k<16 real) ----
    int eA = el[w * 16 + l15];
    short8 a0f = (short8)0, a1f = (short8)0;
    if (ks < 2) {
        const float4* s0 = (const float4*)(degrees + (size_t)eA * OH_ + ks * 8);
        const float4* s1 = (const float4*)(degrees + ((size_t)N_EDGES + eA) * OH_ + ks * 8);
        float4 xa = s0[0], xb = s0[1];
        float4 ya = s1[0], yb = s1[1];
        a0f = __builtin_bit_cast(short8, pack8(xa.x, xa.y, xa.z, xa.w, xb.x, xb.y, xb.z, xb.w));
        a1f = __builtin_bit_cast(short8, pack8(ya.x, ya.y, ya.z, ya.w, yb.x, yb.y, yb.z, yb.w));
    }

#define MFMA_PHASE(p)                                                                  \
    {                                                                                  \
        f32x4 acc0[8], acc1[8];                                                        \
        _Pragma("unroll")                                                              \
        for (int j = 0; j < 8; ++j) { acc0[j] = (f32x4)(0.f); acc1[j] = (f32x4)(0.f); }\
        _Pragma("unroll")                                                              \
        for (int j = 0; j < 8; ++j) {                                                  \
            int n = (p) * 128 + j * 16 + l15;                                          \
            short8 bf = (short8)0;                                                     \
            if (ks < 2) bf = *(const short8*)(WT + (size_t)n * KF_ + 256 + ks * 8);    \
            acc0[j] = __builtin_amdgcn_mfma_f32_16x16x32_bf16(a0f, bf, acc0[j], 0,0,0);\
            acc1[j] = __builtin_amdgcn_mfma_f32_16x16x32_bf16(a1f, bf, acc1[j], 0,0,0);\
        }                                                                              \
        _Pragma("unroll")                                                              \
        for (int j = 0; j < 8; ++j) {                                                  \
            _Pragma("unroll")                                                          \
            for (int i = 0; i < 4; ++i) {                                              \
                int row = w * 16 + ks * 4 + i;                                         \
                Dlds[0][row][j * 16 + l15] = f2bf(acc0[j][i]);                         \
                Dlds[1][row][j * 16 + l15] = f2bf(acc1[j][i]);                         \
            }                                                                          \
        }                                                                              \
    }

#define FLUSH(p, key, r0, r1)                                                          \
    if ((key) >= 0) {                                                                  \
        FL[w][ln][0] = (r0);                                                           \
        FL[w][ln][1] = (r1);                                                           \
        float va = FL[w][(ln >> 1)][ln & 1];                                           \
        float vb = FL[w][32 + (ln >> 1)][ln & 1];                                      \
        atomicAdd(&out[(size_t)(key) * DOUT_ + (p) * 128 + ln], va);                   \
        atomicAdd(&out[(size_t)(key) * DOUT_ + (p) * 128 + 64 + ln], vb);              \
    }

#define REDUCE_PHASE(p, gva, gvb)                                                      \
    {                                                                                  \
        int runkey = tgt[w * 16];                                                      \
        float rs0 = 0.f, rs1 = 0.f;                                                    \
        _Pragma("unroll")                                                              \
        for (int r = 0; r < 16; ++r) {                                                 \
            int row = w * 16 + r;                                                      \
            unsigned int d0u = *(const unsigned int*)&Dlds[0][row][2 * ln];            \
            unsigned int d1u = *(const unsigned int*)&Dlds[1][row][2 * ln];            \
            unsigned int g0u = gva[r], g1u = gvb[r];                                   \
            float la0 = bf2f(g0u & 0xffffu) + bf2f(d0u & 0xffffu);                     \
            float ha0 = bf2f(g0u >> 16) + bf2f(d0u >> 16);                             \
            float la1 = bf2f(g1u & 0xffffu) + bf2f(d1u & 0xffffu);                     \
            float ha1 = bf2f(g1u >> 16) + bf2f(d1u >> 16);                             \
            float v0 = epv * fast_rcp((1.f + __expf(-la0)) * (1.f + __expf(-la1)));    \
            float v1 = epv * fast_rcp((1.f + __expf(-ha0)) * (1.f + __expf(-ha1)));    \
            int k = tgt[row];                                                          \
            if (k != runkey) {                                                         \
                FLUSH(p, runkey, rs0, rs1);                                            \
                runkey = k; rs0 = v0; rs1 = v1;                                        \
            } else { rs0 += v0; rs1 += v1; }                                           \
        }                                                                              \
        FLUSH(p, runkey, rs0, rs1);                                                    \
    }

    MFMA_PHASE(0);

    // ---- phase-1 gathers (cols 128+2ln), in flight across phase-0 reduce ----
    unsigned int gv01[16], gv11[16];
#pragma unroll
    for (int r = 0; r < 16; ++r) {
        int row = w * 16 + r;
        gv01[r] = *(const unsigned int*)(G + (size_t)pl0[row] * DOUT_ + 128 + 2 * ln);
        gv11[r] = *(const unsigned int*)(G + (size_t)pl1[row] * DOUT_ + 128 + 2 * ln);
    }

    __syncthreads();            // D phase-0 visible
    REDUCE_PHASE(0, gv00, gv10);
    __syncthreads();            // all waves done reading D phase-0
    MFMA_PHASE(1);
    __syncthreads();            // D phase-1 visible
    REDUCE_PHASE(1, gv01, gv11);

#undef MFMA_PHASE
#undef FLUSH
#undef REDUCE_PHASE
}

extern "C" void kernel_launch(void* const* d_in, const int* in_sizes, int n_in,
                              void* d_out, int out_size, void* d_ws, size_t ws_size,
                              hipStream_t stream) {
    const float* h        = (const float*)d_in[0];
    const int*   pairs_k0 = (const int*)d_in[1];
    const int*   pairs_k1 = (const int*)d_in[2];
    const float* deg_k0   = (const float*)d_in[3];
    const float* deg_k1   = (const float*)d_in[4];
    const int*   sc_k0    = (const int*)d_in[5];
    const int*   sc_k1    = (const int*)d_in[6];
    const float* W_lin    = (const float*)d_in[7];
    const float* b_lin    = (const float*)d_in[8];
    const float* W_k0     = (const float*)d_in[9];
    const float* b_k0     = (const float*)d_in[10];
    const float* W_k1     = (const float*)d_in[11];
    const float* b_k1     = (const float*)d_in[12];
    const float* eps_k0   = (const float*)d_in[13];
    const float* eps_k1   = (const float*)d_in[14];
    float* out = (float*)d_out;

    size_t ush_elems = (size_t)DOUT_ * DIN_ + 2 * (size_t)DOUT_ * KF_
                     + 3 * (size_t)N_NODES * DIN_;          // h_bf + G0 + G1
    size_t int_elems = 2 * (size_t)N_NODES * 2 + 2 * (size_t)N_EDGES * 2 + 512;
    size_t need = ush_elems * sizeof(unsigned short) + int_elems * sizeof(int);
    if (ws_size < need) return;  // fail loudly in validation

    unsigned short* WT_lin = (unsigned short*)d_ws;
    unsigned short* WT_k0  = WT_lin + DOUT_ * DIN_;
    unsigned short* WT_k1  = WT_k0 + DOUT_ * KF_;
    unsigned short* h_bf   = WT_k1 + DOUT_ * KF_;
    unsigned short* G0     = h_bf + (size_t)N_NODES * DIN_;
    unsigned short* G1     = G0 + (size_t)N_NODES * DIN_;
    int* hist     = (int*)(G1 + (size_t)N_NODES * DIN_);
    int* offs     = hist + 2 * N_NODES;
    int* order    = offs + 2 * N_NODES;     // [2*E]
    int* keys     = order + 2 * N_EDGES;    // [2*E]
    int* partials = keys + 2 * N_EDGES;     // [512]

    hipMemsetAsync(hist, 0, 2 * N_NODES * sizeof(int), stream);
    hist_kernel<<<(N_EDGES + 255) / 256, 256, 0, stream>>>(sc_k0, sc_k1, hist);
    scan_pass1<<<SCAN_NB, 256, 0, stream>>>(hist, partials);
    scan_pass2<<<1, 512, 0, stream>>>(partials);
    scan_pass3<<<SCAN_NB, 256, 0, stream>>>(hist, partials, offs);
    rank_kernel<<<(N_EDGES + 255) / 256, 256, 0, stream>>>(sc_k0, sc_k1, offs, order, keys);

    prep_weights<<<(DOUT_ * KF_ + 255) / 256, 256, 0, stream>>>(W_lin, W_k0, W_k1,
                                                                WT_lin, WT_k0, WT_k1);
    conv_h<<<(N_NODES * DIN_ / 8) / 256, 256, 0, stream>>>(h, h_bf);
    lin_gemms<<<3 * NBLK_G, 256, 0, stream>>>(h_bf, WT_lin, WT_k0, WT_k1,
                                              b_lin, b_k0, b_k1, out, G0, G1);
    edge_fused<<<2 * NBLK_EDGE, 256, 0, stream>>>(G0, G1, pairs_k0, pairs_k1,
                                                  deg_k0, deg_k1, order, keys,
                                                  WT_k0, WT_k1, eps_k0, eps_k1, out);
}

// Round 9
// 362.617 us; speedup vs baseline: 2.0484x; 1.0305x over previous
//
#include <hip/hip_runtime.h>
#include <hip/hip_bf16.h>

#define N_NODES 50000
#define N_EDGES 250000
#define DIN_ 256
#define DOUT_ 256
#define OH_ 16
#define KF_ 288   // 256 (h) + 16 (degrees) + 16 zero-pad
#define NBLK_EDGE ((N_EDGES + 63) / 64)     // 3907
#define NBLK_G ((N_NODES + 63) / 64)        // 782
#define SCAN_TOT (2 * N_NODES)              // 100000
#define SCAN_NB ((SCAN_TOT + 255) / 256)    // 391

typedef short short8 __attribute__((ext_vector_type(8)));
typedef float f32x4 __attribute__((ext_vector_type(4)));

__device__ __forceinline__ unsigned short f2bf(float f) {
    unsigned u = __builtin_bit_cast(unsigned, f);
    return (unsigned short)((u + 0x7fffu + ((u >> 16) & 1u)) >> 16);
}

__device__ __forceinline__ float bf2f(unsigned v) {
    return __builtin_bit_cast(float, v << 16);
}

__device__ __forceinline__ uint4 pack8(float f0, float f1, float f2, float f3,
                                       float f4, float f5, float f6, float f7) {
    uint4 u;
    u.x = (unsigned)f2bf(f0) | ((unsigned)f2bf(f1) << 16);
    u.y = (unsigned)f2bf(f2) | ((unsigned)f2bf(f3) << 16);
    u.z = (unsigned)f2bf(f4) | ((unsigned)f2bf(f5) << 16);
    u.w = (unsigned)f2bf(f6) | ((unsigned)f2bf(f7) << 16);
    return u;
}

__device__ __forceinline__ float fast_rcp(float x) {
#if __has_builtin(__builtin_amdgcn_rcpf)
    return __builtin_amdgcn_rcpf(x);
#else
    return 1.0f / x;
#endif
}

// async global -> LDS, 16 bytes per lane (dest = wave-uniform base + lane*16)
__device__ __forceinline__ void gl_lds16(const void* g, void* l) {
    __builtin_amdgcn_global_load_lds(
        (const __attribute__((address_space(1))) unsigned int*)g,
        (__attribute__((address_space(3))) unsigned int*)l, 16, 0, 0);
}

// ---------- sort pipeline: counting sort of edges by scatter target ----------
__global__ void hist_kernel(const int* __restrict__ sc0, const int* __restrict__ sc1,
                            int* __restrict__ hist) {
    int e = blockIdx.x * 256 + threadIdx.x;
    if (e < N_EDGES) {
        atomicAdd(&hist[sc0[e]], 1);
        atomicAdd(&hist[N_NODES + sc1[e]], 1);
    }
}

__global__ void scan_pass1(const int* __restrict__ hist, int* __restrict__ partials) {
    __shared__ int sdata[256];
    int gid = blockIdx.x * 256 + threadIdx.x;
    sdata[threadIdx.x] = (gid < SCAN_TOT) ? hist[gid] : 0;
    __syncthreads();
    for (int d = 128; d > 0; d >>= 1) {
        if (threadIdx.x < d) sdata[threadIdx.x] += sdata[threadIdx.x + d];
        __syncthreads();
    }
    if (threadIdx.x == 0) partials[blockIdx.x] = sdata[0];
}

__global__ __launch_bounds__(512) void scan_pass2(int* __restrict__ partials) {
    __shared__ int s[512];
    int t = threadIdx.x;
    s[t] = (t < SCAN_NB) ? partials[t] : 0;
    __syncthreads();
    for (int d = 1; d < 512; d <<= 1) {
        int add = (t >= d) ? s[t - d] : 0;
        __syncthreads();
        s[t] += add;
        __syncthreads();
    }
    if (t < SCAN_NB) partials[t] = (t == 0) ? 0 : s[t - 1];   // exclusive
}

__global__ void scan_pass3(const int* __restrict__ hist, const int* __restrict__ partials,
                           int* __restrict__ offs) {
    __shared__ int s[256];
    int gid = blockIdx.x * 256 + threadIdx.x;
    int t = threadIdx.x;
    int v = (gid < SCAN_TOT) ? hist[gid] : 0;
    s[t] = v;
    __syncthreads();
    for (int d = 1; d < 256; d <<= 1) {
        int add = (t >= d) ? s[t - d] : 0;
        __syncthreads();
        s[t] += add;
        __syncthreads();
    }
    if (gid < SCAN_TOT) offs[gid] = partials[blockIdx.x] + s[t] - v;  // exclusive
}

__global__ void rank_kernel(const int* __restrict__ sc0, const int* __restrict__ sc1,
                            int* __restrict__ offs, int* __restrict__ order,
                            int* __restrict__ keys) {
    int e = blockIdx.x * 256 + threadIdx.x;
    if (e < N_EDGES) {
        int k0 = sc0[e];
        int p = atomicAdd(&offs[k0], 1);
        order[p] = e; keys[p] = k0;
        int k1 = sc1[e];
        int q = atomicAdd(&offs[N_NODES + k1], 1);
        order[q] = e; keys[q] = k1;
    }
}

// ---------- weight / input prep ----------
__global__ void prep_weights(const float* __restrict__ W_lin,
                             const float* __restrict__ W_k0,
                             const float* __restrict__ W_k1,
                             unsigned short* __restrict__ WT_lin,
                             unsigned short* __restrict__ WT_k0,
                             unsigned short* __restrict__ WT_k1) {
    int idx = blockIdx.x * 256 + threadIdx.x;
    if (idx < DOUT_ * DIN_) {
        int n = idx >> 8, k = idx & 255;
        WT_lin[idx] = f2bf(W_lin[k * DOUT_ + n]);
    }
    if (idx < DOUT_ * KF_) {
        int n = idx / KF_, k = idx - n * KF_;
        float v0 = 0.f, v1 = 0.f;
        if (k < DIN_ + OH_) {
            v0 = W_k0[k * DOUT_ + n];
            v1 = W_k1[k * DOUT_ + n];
        }
        WT_k0[idx] = f2bf(v0);
        WT_k1[idx] = f2bf(v1);
    }
}

__global__ void conv_h(const float* __restrict__ h, unsigned short* __restrict__ hbf) {
    int idx = blockIdx.x * 256 + threadIdx.x;
    const float4* s = (const float4*)(h + (size_t)idx * 8);
    float4 a = s[0], b = s[1];
    ((uint4*)hbf)[idx] = pack8(a.x, a.y, a.z, a.w, b.x, b.y, b.z, b.w);
}

// Three 50000x256x256 GEMMs in one launch:
//   kb=0: G0 = h@W_k0[:256]+b_k0 (bf16), kb=1: G1 likewise, kb=2: out = h@W_lin+b_lin (f32)
__global__ __launch_bounds__(256) void lin_gemms(const unsigned short* __restrict__ hbf,
                                                 const unsigned short* __restrict__ WT_lin,
                                                 const unsigned short* __restrict__ WTk0,
                                                 const unsigned short* __restrict__ WTk1,
                                                 const float* __restrict__ b_lin,
                                                 const float* __restrict__ bk0,
                                                 const float* __restrict__ bk1,
                                                 float* __restrict__ out,
                                                 unsigned short* __restrict__ G0,
                                                 unsigned short* __restrict__ G1) {
    __shared__ unsigned short Alds[2][64][32];
    __shared__ unsigned short Blds[2][256][32];
    __shared__ float bias_lds[256];
    int kb = blockIdx.x / NBLK_G;
    int bx = blockIdx.x - kb * NBLK_G;
    const unsigned short* WT; const float* bias; int stride;
    if (kb == 0)      { WT = WTk0;   bias = bk0;   stride = KF_; }
    else if (kb == 1) { WT = WTk1;   bias = bk1;   stride = KF_; }
    else              { WT = WT_lin; bias = b_lin; stride = DIN_; }

    int tid = threadIdx.x;
    int w = tid >> 6, ln = tid & 63, l15 = ln & 15;
    int row0 = bx * 64;
    bias_lds[tid] = bias[tid];

    int ar = row0 + w * 16 + (ln >> 2);
    if (ar >= N_NODES) ar = N_NODES - 1;
    int qs = (ln & 3) ^ ((ln >> 3) & 3);
    const unsigned short* asrc = hbf + (size_t)ar * DIN_ + qs * 8;
    int brow = w * 64;
    int swz = ((ln >> 4) ^ ((l15 >> 1) & 3)) * 8;

    f32x4 acc[16];
#pragma unroll
    for (int j = 0; j < 16; ++j) acc[j] = (f32x4)(0.f);

    gl_lds16(asrc, &Alds[0][w * 16][0]);
#pragma unroll
    for (int i = 0; i < 4; ++i) {
        int n = brow + i * 16 + (ln >> 2);
        gl_lds16(WT + (size_t)n * stride + qs * 8, &Blds[0][brow + i * 16][0]);
    }
    __syncthreads();

    int buf = 0;
    for (int kk = 0; kk < 8; ++kk) {
        if (kk < 7) {
            gl_lds16(asrc + (kk + 1) * 32, &Alds[buf ^ 1][w * 16][0]);
#pragma unroll
            for (int i = 0; i < 4; ++i) {
                int n = brow + i * 16 + (ln >> 2);
                gl_lds16(WT + (size_t)n * stride + (kk + 1) * 32 + qs * 8,
                         &Blds[buf ^ 1][brow + i * 16][0]);
            }
        }
        short8 af = *(const short8*)&Alds[buf][w * 16 + l15][swz];
#pragma unroll
        for (int j = 0; j < 16; ++j) {
            short8 bf = *(const short8*)&Blds[buf][j * 16 + l15][swz];
            acc[j] = __builtin_amdgcn_mfma_f32_16x16x32_bf16(af, bf, acc[j], 0, 0, 0);
        }
        __syncthreads();
        buf ^= 1;
    }

    int rbase = row0 + w * 16 + ((ln >> 4) << 2);
    unsigned short* G = (kb == 0) ? G0 : G1;
#pragma unroll
    for (int j = 0; j < 16; ++j) {
        int n = j * 16 + l15;
        float bv = bias_lds[n];
#pragma unroll
        for (int i = 0; i < 4; ++i) {
            int rr = rbase + i;
            if (rr < N_NODES) {
                float v = acc[j][i] + bv;
                if (kb == 2) out[(size_t)rr * DOUT_ + n] = v;
                else         G[(size_t)rr * DOUT_ + n] = f2bf(v);
            }
        }
    }
}

// Fused edge epilogue v3: nontemporal streams (preserve L3 for G), 128-VGPR budget
// for gather ILP, t-packed D in LDS (b32 writes / b64 reads).
__global__ __launch_bounds__(256, 4) void edge_fused(const unsigned short* __restrict__ Gk0,
                                                     const unsigned short* __restrict__ Gk1,
                                                     const int* __restrict__ pairs0,
                                                     const int* __restrict__ pairs1,
                                                     const float* __restrict__ deg0,
                                                     const float* __restrict__ deg1,
                                                     const int* __restrict__ order_all,
                                                     const int* __restrict__ keys_all,
                                                     const unsigned short* __restrict__ WT0,
                                                     const unsigned short* __restrict__ WT1,
                                                     const float* __restrict__ eps0,
                                                     const float* __restrict__ eps1,
                                                     float* __restrict__ out) {
    __shared__ unsigned int Dlds[64][132];   // 33.8 KB, t-packed D for one 128-col phase
    __shared__ float FL[4][64][2];           // 2 KB flush-transpose buffers
    __shared__ int tgt[64], pl0[64], pl1[64], el[64];
    int kb = (blockIdx.x >= NBLK_EDGE) ? 1 : 0;
    int bx = blockIdx.x - kb * NBLK_EDGE;
    const unsigned short* G = kb ? Gk1 : Gk0;
    const int* pairs = kb ? pairs1 : pairs0;
    const float* degrees = kb ? deg1 : deg0;
    const int* order_k = order_all + kb * N_EDGES;
    const int* keys_k  = keys_all + kb * N_EDGES;
    const unsigned short* WT = kb ? WT1 : WT0;
    float epv = 1.0f + (kb ? eps1[0] : eps0[0]);

    int tid = threadIdx.x;
    int w = tid >> 6, ln = tid & 63, l15 = ln & 15, ks = ln >> 4;
    int e0 = bx * 64;
    if (tid < 64) {
        int s = e0 + tid;
        int sc = (s < N_EDGES) ? s : N_EDGES - 1;
        int e = __builtin_nontemporal_load(order_k + sc);
        el[tid]  = e;
        tgt[tid] = (s < N_EDGES) ? __builtin_nontemporal_load(keys_k + s) : -1;
        pl0[tid] = __builtin_nontemporal_load(pairs + e);
        pl1[tid] = __builtin_nontemporal_load(pairs + N_EDGES + e);
    }
    __syncthreads();

    // ---- phase-0 gathers: cols [2ln, 2ln+1] of each of this wave's 16 G-row pairs ----
    unsigned int gv00[16], gv10[16];
#pragma unroll
    for (int r = 0; r < 16; ++r) {
        int row = w * 16 + r;
        gv00[r] = *(const unsigned int*)(G + (size_t)pl0[row] * DOUT_ + 2 * ln);
        gv10[r] = *(const unsigned int*)(G + (size_t)pl1[row] * DOUT_ + 2 * ln);
    }

    // ---- A-frags from degrees (K=32, k<16 real), nontemporal (read-once stream) ----
    int eA = el[w * 16 + l15];
    short8 a0f = (short8)0, a1f = (short8)0;
    if (ks < 2) {
        const f32x4* s0 = (const f32x4*)(degrees + (size_t)eA * OH_ + ks * 8);
        const f32x4* s1 = (const f32x4*)(degrees + ((size_t)N_EDGES + eA) * OH_ + ks * 8);
        f32x4 xa = __builtin_nontemporal_load(s0);
        f32x4 xb = __builtin_nontemporal_load(s0 + 1);
        f32x4 ya = __builtin_nontemporal_load(s1);
        f32x4 yb = __builtin_nontemporal_load(s1 + 1);
        a0f = __builtin_bit_cast(short8, pack8(xa[0], xa[1], xa[2], xa[3],
                                               xb[0], xb[1], xb[2], xb[3]));
        a1f = __builtin_bit_cast(short8, pack8(ya[0], ya[1], ya[2], ya[3],
                                               yb[0], yb[1], yb[2], yb[3]));
    }

#define MFMA_PHASE(p)                                                                  \
    {                                                                                  \
        f32x4 acc0[8], acc1[8];                                                        \
        _Pragma("unroll")                                                              \
        for (int j = 0; j < 8; ++j) { acc0[j] = (f32x4)(0.f); acc1[j] = (f32x4)(0.f); }\
        _Pragma("unroll")                                                              \
        for (int j = 0; j < 8; ++j) {                                                  \
            int n = (p) * 128 + j * 16 + l15;                                          \
            short8 bf = (short8)0;                                                     \
            if (ks < 2) bf = *(const short8*)(WT + (size_t)n * KF_ + 256 + ks * 8);    \
            acc0[j] = __builtin_amdgcn_mfma_f32_16x16x32_bf16(a0f, bf, acc0[j], 0,0,0);\
            acc1[j] = __builtin_amdgcn_mfma_f32_16x16x32_bf16(a1f, bf, acc1[j], 0,0,0);\
        }                                                                              \
        _Pragma("unroll")                                                              \
        for (int j = 0; j < 8; ++j) {                                                  \
            _Pragma("unroll")                                                          \
            for (int i = 0; i < 4; ++i) {                                              \
                int row = w * 16 + ks * 4 + i;                                         \
                Dlds[row][j * 16 + l15] = (unsigned)f2bf(acc0[j][i])                   \
                                        | ((unsigned)f2bf(acc1[j][i]) << 16);          \
            }                                                                          \
        }                                                                              \
    }

#define FLUSH(p, key, r0, r1)                                                          \
    if ((key) >= 0) {                                                                  \
        FL[w][ln][0] = (r0);                                                           \
        FL[w][ln][1] = (r1);                                                           \
        float va = FL[w][(ln >> 1)][ln & 1];                                           \
        float vb = FL[w][32 + (ln >> 1)][ln & 1];                                      \
        atomicAdd(&out[(size_t)(key) * DOUT_ + (p) * 128 + ln], va);                   \
        atomicAdd(&out[(size_t)(key) * DOUT_ + (p) * 128 + 64 + ln], vb);              \
    }

#define REDUCE_PHASE(p, gva, gvb)                                                      \
    {                                                                                  \
        int runkey = tgt[w * 16];                                                      \
        float rs0 = 0.f, rs1 = 0.f;                                                    \
        _Pragma("unroll")                                                              \
        for (int r = 0; r < 16; ++r) {                                                 \
            int row = w * 16 + r;                                                      \
            uint2 dp = *(const uint2*)&Dlds[row][2 * ln];                              \
            unsigned int g0u = gva[r], g1u = gvb[r];                                   \
            float la0 = bf2f(g0u & 0xffffu) + bf2f(dp.x & 0xffffu);                    \
            float la1 = bf2f(g1u & 0xffffu) + bf2f(dp.x >> 16);                        \
            float ha0 = bf2f(g0u >> 16) + bf2f(dp.y & 0xffffu);                        \
            float ha1 = bf2f(g1u >> 16) + bf2f(dp.y >> 16);                            \
            float v0 = epv * fast_rcp((1.f + __expf(-la0)) * (1.f + __expf(-la1)));    \
            float v1 = epv * fast_rcp((1.f + __expf(-ha0)) * (1.f + __expf(-ha1)));    \
            int k = tgt[row];                                                          \
            if (k != runkey) {                                                         \
                FLUSH(p, runkey, rs0, rs1);                                            \
                runkey = k; rs0 = v0; rs1 = v1;                                        \
            } else { rs0 += v0; rs1 += v1; }                                           \
        }                                                                              \
        FLUSH(p, runkey, rs0, rs1);                                                    \
    }

    MFMA_PHASE(0);

    // ---- phase-1 gathers (cols 128+2ln), in flight across phase-0 reduce ----
    unsigned int gv01[16], gv11[16];
#pragma unroll
    for (int r = 0; r < 16; ++r) {
        int row = w * 16 + r;
        gv01[r] = *(const unsigned int*)(G + (size_t)pl0[row] * DOUT_ + 128 + 2 * ln);
        gv11[r] = *(const unsigned int*)(G + (size_t)pl1[row] * DOUT_ + 128 + 2 * ln);
    }

    __syncthreads();            // D phase-0 visible
    REDUCE_PHASE(0, gv00, gv10);
    __syncthreads();            // all waves done reading D phase-0
    MFMA_PHASE(1);
    __syncthreads();            // D phase-1 visible
    REDUCE_PHASE(1, gv01, gv11);

#undef MFMA_PHASE
#undef FLUSH
#undef REDUCE_PHASE
}

extern "C" void kernel_launch(void* const* d_in, const int* in_sizes, int n_in,
                              void* d_out, int out_size, void* d_ws, size_t ws_size,
                              hipStream_t stream) {
    const float* h        = (const float*)d_in[0];
    const int*   pairs_k0 = (const int*)d_in[1];
    const int*   pairs_k1 = (const int*)d_in[2];
    const float* deg_k0   = (const float*)d_in[3];
    const float* deg_k1   = (const float*)d_in[4];
    const int*   sc_k0    = (const int*)d_in[5];
    const int*   sc_k1    = (const int*)d_in[6];
    const float* W_lin    = (const float*)d_in[7];
    const float* b_lin    = (const float*)d_in[8];
    const float* W_k0     = (const float*)d_in[9];
    const float* b_k0     = (const float*)d_in[10];
    const float* W_k1     = (const float*)d_in[11];
    const float* b_k1     = (const float*)d_in[12];
    const float* eps_k0   = (const float*)d_in[13];
    const float* eps_k1   = (const float*)d_in[14];
    float* out = (float*)d_out;

    size_t ush_elems = (size_t)DOUT_ * DIN_ + 2 * (size_t)DOUT_ * KF_
                     + 3 * (size_t)N_NODES * DIN_;          // h_bf + G0 + G1
    size_t int_elems = 2 * (size_t)N_NODES * 2 + 2 * (size_t)N_EDGES * 2 + 512;
    size_t need = ush_elems * sizeof(unsigned short) + int_elems * sizeof(int);
    if (ws_size < need) return;  // fail loudly in validation

    unsigned short* WT_lin = (unsigned short*)d_ws;
    unsigned short* WT_k0  = WT_lin + DOUT_ * DIN_;
    unsigned short* WT_k1  = WT_k0 + DOUT_ * KF_;
    unsigned short* h_bf   = WT_k1 + DOUT_ * KF_;
    unsigned short* G0     = h_bf + (size_t)N_NODES * DIN_;
    unsigned short* G1     = G0 + (size_t)N_NODES * DIN_;
    int* hist     = (int*)(G1 + (size_t)N_NODES * DIN_);
    int* offs     = hist + 2 * N_NODES;
    int* order    = offs + 2 * N_NODES;     // [2*E]
    int* keys     = order + 2 * N_EDGES;    // [2*E]
    int* partials = keys + 2 * N_EDGES;     // [512]

    hipMemsetAsync(hist, 0, 2 * N_NODES * sizeof(int), stream);
    hist_kernel<<<(N_EDGES + 255) / 256, 256, 0, stream>>>(sc_k0, sc_k1, hist);
    scan_pass1<<<SCAN_NB, 256, 0, stream>>>(hist, partials);
    scan_pass2<<<1, 512, 0, stream>>>(partials);
    scan_pass3<<<SCAN_NB, 256, 0, stream>>>(hist, partials, offs);
    rank_kernel<<<(N_EDGES + 255) / 256, 256, 0, stream>>>(sc_k0, sc_k1, offs, order, keys);

    prep_weights<<<(DOUT_ * KF_ + 255) / 256, 256, 0, stream>>>(W_lin, W_k0, W_k1,
                                                                WT_lin, WT_k0, WT_k1);
    conv_h<<<(N_NODES * DIN_ / 8) / 256, 256, 0, stream>>>(h, h_bf);
    lin_gemms<<<3 * NBLK_G, 256, 0, stream>>>(h_bf, WT_lin, WT_k0, WT_k1,
                                              b_lin, b_k0, b_k1, out, G0, G1);
    edge_fused<<<2 * NBLK_EDGE, 256, 0, stream>>>(G0, G1, pairs_k0, pairs_k1,
                                                  deg_k0, deg_k1, order, keys,
                                                  WT_k0, WT_k1, eps_k0, eps_k1, out);
}